// Round 11
// baseline (26.281 us; speedup 1.0000x reference)
//
#include <hip/hip_runtime.h>

// Problem constants (from the reference file)
constexpr int kC = 3;
constexpr int kH = 2048;
constexpr int kW = 2048;
constexpr int kNB = 256;      // N_BOXES
constexpr int kHeight = 32;   // HEIGHT

typedef float f32x4 __attribute__((ext_vector_type(4)));

// Select element idx (0..7) from {a[0..3], b[0..3]} via cndmask tree
// (static indexing only — dynamic index would spill to scratch).
__device__ __forceinline__ float sel8(f32x4 a, f32x4 b, int idx) {
    const f32x4 h = (idx & 4) ? b : a;
    const float e0 = (idx & 2) ? h[2] : h[0];
    const float e1 = (idx & 2) ? h[3] : h[1];
    return (idx & 1) ? e1 : e0;
}

// R3-champion structure (64-thr blocks, 4 cols/thread, NT dwordx4 stores).
// New: fast gather path — one row, two aligned dwordx4 loads per channel
// (6 vmem loads/thread instead of 12), in-register column selection.
// Values bitwise-identical to scalar gather; scalar fallback if the 4 cols
// straddle rows (ulp-rare) or exceed the 8-px window.
__global__ __launch_bounds__(64) void extract_kernel(
    const float* __restrict__ img,
    const float* __restrict__ boxes,
    const float* __restrict__ scale,
    float* __restrict__ out,
    int max_w)
{
#pragma clang fp contract(off)
    const int r = blockIdx.y;
    const int b = blockIdx.z;
    const int c0 = (blockIdx.x * 64 + threadIdx.x) * 4;
    if (c0 >= max_w) return;

    const float s = scale[0];
    const float* bx = boxes + b * 8;      // boxes[b, 4, 2]
    const float p0x = bx[0] / s, p0y = bx[1] / s;
    const float p1x = bx[2] / s, p1y = bx[3] / s;
    const float p2x = bx[4] / s, p2y = bx[5] / s;
    const float p3x = bx[6] / s, p3y = bx[7] / s;

    const float hdx = p2x - p1x, hdy = p2y - p1y;
    const float h_dist = sqrtf(hdx * hdx + hdy * hdy);
    const float wdx = p1x - p0x, wdy = p1y - p0y;
    const float w_dist = sqrtf(wdx * wdx + wdy * wdy);
    const int width = (int)(32.0f * w_dist / fmaxf(h_dist, 1e-6f));
    const float curr_w = (float)width;

    if (r == 0 && c0 == 0) {
        out[(size_t)kNB * kC * kHeight * max_w + b] = (float)(width / 8 * 8 + 8);
    }

    const size_t ch_stride = (size_t)kHeight * max_w;
    const size_t obase = (((size_t)b * kC) * (size_t)kHeight + (size_t)r) * (size_t)max_w + (size_t)c0;

    f32x4 o0 = {0.f, 0.f, 0.f, 0.f};
    f32x4 o1 = {0.f, 0.f, 0.f, 0.f};
    f32x4 o2 = {0.f, 0.f, 0.f, 0.f};

    if (c0 < width) {
        const float y = (float)r / 31.0f;
        const float omy = 1.0f - y;
        const float xden = fmaxf(curr_w - 1.0f, 1.0f);

        int  ixc[4], iyc[4];
        bool inb[4], act[4];
#pragma unroll
        for (int j = 0; j < 4; ++j) {
            const float cf = (float)(c0 + j);
            act[j] = (cf < curr_w);
            const float x = cf / xden;
            const float omx = 1.0f - x;
            const float w00 = omx * omy;
            const float w10 = x * omy;
            const float w11 = x * y;
            const float w01 = omx * y;
            const float res_x = w00 * p0x + w10 * p1x + w11 * p2x + w01 * p3x;
            const float res_y = w00 * p0y + w10 * p1y + w11 * p2y + w01 * p3y;
            const float grid_c = res_x / 2047.0f * 2.0f - 1.0f;
            const float grid_r = res_y / 2047.0f * 2.0f - 1.0f;
            const float fix = rintf((grid_c + 1.0f) * 2047.0f * 0.5f);
            const float fiy = rintf((grid_r + 1.0f) * 2047.0f * 0.5f);
            inb[j] = (fix >= 0.0f) && (fix <= 2047.0f) &&
                     (fiy >= 0.0f) && (fiy <= 2047.0f) && act[j];
            ixc[j] = (int)fminf(fmaxf(fix, 0.0f), 2047.0f);
            iyc[j] = (int)fminf(fmaxf(fiy, 0.0f), 2047.0f);
        }

        // Fast path: one row, 8-px aligned window holds all 4 columns.
        int base = ixc[0] & ~3;
        if (base > kW - 8) base = kW - 8;
        const int i0 = ixc[0] - base, i1 = ixc[1] - base,
                  i2 = ixc[2] - base, i3 = ixc[3] - base;
        const bool fast =
            (iyc[1] == iyc[0]) && (iyc[2] == iyc[0]) && (iyc[3] == iyc[0]) &&
            ((unsigned)(i0 | i1 | i2 | i3) <= 7u);

        if (fast) {
            const size_t rowoff = (size_t)iyc[0] * kW + (size_t)base;
            const float* r0 = img + rowoff;
            const float* r1 = img + (size_t)kH * kW + rowoff;
            const float* r2 = img + 2 * (size_t)kH * kW + rowoff;
            const f32x4 a0 = *(const f32x4*)r0, b0 = *(const f32x4*)(r0 + 4);
            const f32x4 a1 = *(const f32x4*)r1, b1 = *(const f32x4*)(r1 + 4);
            const f32x4 a2 = *(const f32x4*)r2, b2 = *(const f32x4*)(r2 + 4);
            o0[0] = inb[0] ? sel8(a0, b0, i0) : 0.0f;
            o0[1] = inb[1] ? sel8(a0, b0, i1) : 0.0f;
            o0[2] = inb[2] ? sel8(a0, b0, i2) : 0.0f;
            o0[3] = inb[3] ? sel8(a0, b0, i3) : 0.0f;
            o1[0] = inb[0] ? sel8(a1, b1, i0) : 0.0f;
            o1[1] = inb[1] ? sel8(a1, b1, i1) : 0.0f;
            o1[2] = inb[2] ? sel8(a1, b1, i2) : 0.0f;
            o1[3] = inb[3] ? sel8(a1, b1, i3) : 0.0f;
            o2[0] = inb[0] ? sel8(a2, b2, i0) : 0.0f;
            o2[1] = inb[1] ? sel8(a2, b2, i1) : 0.0f;
            o2[2] = inb[2] ? sel8(a2, b2, i2) : 0.0f;
            o2[3] = inb[3] ? sel8(a2, b2, i3) : 0.0f;
        } else {
            // Bit-exact scalar fallback (rare: row straddle / window overflow)
#pragma unroll
            for (int j = 0; j < 4; ++j) {
                if (act[j]) {
                    const size_t ipix = (size_t)iyc[j] * kW + (size_t)ixc[j];
                    o0[j] = inb[j] ? img[ipix] : 0.0f;
                    o1[j] = inb[j] ? img[(size_t)kH * kW + ipix] : 0.0f;
                    o2[j] = inb[j] ? img[2 * (size_t)kH * kW + ipix] : 0.0f;
                }
            }
        }
    }

    // 16B-aligned (max_w % 8 == 0, c0 % 4 == 0) streaming stores.
    __builtin_nontemporal_store(o0, (f32x4*)(out + obase));
    __builtin_nontemporal_store(o1, (f32x4*)(out + obase + ch_stride));
    __builtin_nontemporal_store(o2, (f32x4*)(out + obase + 2 * ch_stride));
}

extern "C" void kernel_launch(void* const* d_in, const int* in_sizes, int n_in,
                              void* d_out, int out_size, void* d_ws, size_t ws_size,
                              hipStream_t stream) {
    const float* img   = (const float*)d_in[0];
    const float* boxes = (const float*)d_in[1];
    const float* scale = (const float*)d_in[2];
    float* out = (float*)d_out;

    // out_size = NB*C*HEIGHT*max_w + NB  ->  max_w recoverable (multiple of 8)
    const int max_w = (out_size - kNB) / (kNB * kC * kHeight);
    const int quads = max_w / 4;

    dim3 grid((quads + 63) / 64, kHeight, kNB);
    extract_kernel<<<grid, dim3(64, 1, 1), 0, stream>>>(img, boxes, scale, out, max_w);
}